// Round 5
// baseline (310.110 us; speedup 1.0000x reference)
//
#include <hip/hip_runtime.h>
#include <hip/hip_bf16.h>

typedef __attribute__((ext_vector_type(4))) float floatx4;
typedef __attribute__((ext_vector_type(8))) short shortx8;

#define NB   16
#define CIN  256
#define COUT 256
#define KW   3
#define LL   4096
#define LLP  4098   // LL + 2 guard rows (zeros) per b in xt
#define NR   5
#define QK   768    // CIN*KW
#define NP   65536  // NB*LL

static __device__ __forceinline__ unsigned short bf16bits(float f) {
    __hip_bfloat16 h = __float2bfloat16(f);
    return __builtin_bit_cast(unsigned short, h);
}

// async global->LDS, 16B per lane, LDS dest = wave-uniform base + lane*16
static __device__ __forceinline__ void gload16(const void* g, void* l) {
    __builtin_amdgcn_global_load_lds(
        (const __attribute__((address_space(1))) void*)g,
        (__attribute__((address_space(3))) void*)l, 16, 0, 0);
}

// ---------------- K0b: weights -> bf16, zero fr buffer, zero xt guard rows ----------------
__global__ void k_wprep(const float* __restrict__ bk, __hip_bfloat16* __restrict__ wb,
                        float* __restrict__ frz, __hip_bfloat16* __restrict__ xt) {
    int i = blockIdx.x * 256 + threadIdx.x;
    if (i < NP * NR) frz[i] = 0.f;
    if (i < NB * 2 * CIN) {   // guard rows 0,1 of each b-slab = causal zeros
        int bb = i >> 9, rr = i & 511;
        xt[(size_t)bb * LLP * CIN + rr] = __float2bfloat16(0.f);
    }
    if (i >= NR * COUT * QK) return;
    int m = i / QK, q = i % QK;
    int o = (m / 80) * 16 + (m & 15);
    int r = (m % 80) / 16;
    int k = q >> 8, cin = q & 255;
    wb[i] = __float2bfloat16(bk[((r * COUT + o) * CIN + cin) * KW + k]);
}

// ---------------- K1: fused transpose + controller partial logits ----------------
__global__ void k_tfr(const float* __restrict__ x, const float* __restrict__ cw,
                      __hip_bfloat16* __restrict__ xt, float* __restrict__ logit) {
    __shared__ float t[66][65];        // row = l_local+2 (halo rows 0,1), col = cin
    __shared__ float cwsh[64 * 15];    // cw slice for this cin group
    int l0 = blockIdx.x * 64, c0 = blockIdx.y * 64, b = blockIdx.z;
    int tid = threadIdx.x;
    int r16 = tid >> 4, q16 = tid & 15;

    for (int i = tid; i < 64 * 15; i += 256) cwsh[i] = cw[c0 * 15 + i];

    #pragma unroll
    for (int pass = 0; pass < 4; ++pass) {
        int cin = pass * 16 + r16;
        float4 v = *(const float4*)&x[((size_t)(b * CIN + c0 + cin)) * LL + l0 + q16 * 4];
        t[q16 * 4 + 2][cin] = v.x;
        t[q16 * 4 + 3][cin] = v.y;
        t[q16 * 4 + 4][cin] = v.z;
        t[q16 * 4 + 5][cin] = v.w;
    }
    if (tid < 128) {  // halo columns l0-2, l0-1 (zeros at l0==0: causal pad)
        int cin = tid >> 1, j = tid & 1;
        float v = 0.f;
        if (l0 > 0) v = x[((size_t)(b * CIN + c0 + cin)) * LL + l0 - 2 + j];
        t[j][cin] = v;
    }
    __syncthreads();

    // transpose write: xt[b, 2+l, cin] bf16 (guard-row layout)
    #pragma unroll
    for (int pass = 0; pass < 4; ++pass) {
        int lr = pass * 16 + r16;
        int c4 = q16 * 4;
        ushort4 u;
        u.x = bf16bits(t[lr + 2][c4 + 0]);
        u.y = bf16bits(t[lr + 2][c4 + 1]);
        u.z = bf16bits(t[lr + 2][c4 + 2]);
        u.w = bf16bits(t[lr + 2][c4 + 3]);
        *(ushort4*)&xt[((size_t)(b * LLP + 2 + l0 + lr)) * CIN + c0 + c4] = u;
    }

    // controller partials: 4 threads per position, 16 cins each
    int p = tid >> 2, q = tid & 3;
    float lg[NR] = {0.f, 0.f, 0.f, 0.f, 0.f};
    #pragma unroll 4
    for (int ci = 0; ci < 16; ++ci) {
        int cin = q * 16 + ci;
        float x0 = t[p][cin], x1 = t[p + 1][cin], x2 = t[p + 2][cin];
        const float* w = &cwsh[cin * 15];
        #pragma unroll
        for (int n = 0; n < NR; ++n)
            lg[n] += x0 * w[n] + x1 * w[5 + n] + x2 * w[10 + n];
    }
    #pragma unroll
    for (int n = 0; n < NR; ++n) {
        lg[n] += __shfl_xor(lg[n], 1);
        lg[n] += __shfl_xor(lg[n], 2);
    }
    if (q == 0) {
        float* lp = &logit[(size_t)(b * LL + l0 + p) * NR];
        #pragma unroll
        for (int n = 0; n < NR; ++n) atomicAdd(&lp[n], lg[n]);
    }
}

// ---------------- K1b: softmax in-place on fr buffer ----------------
__global__ void k_softmax(const float* __restrict__ cb, float* __restrict__ fr) {
    int p = blockIdx.x * 256 + threadIdx.x;
    if (p >= NP) return;
    float l2[NR];
    #pragma unroll
    for (int n = 0; n < NR; ++n) l2[n] = fr[(size_t)p * NR + n] + cb[n];
    float m = l2[0];
    #pragma unroll
    for (int n = 1; n < NR; ++n) m = fmaxf(m, l2[n]);
    float e[NR], s = 0.f;
    #pragma unroll
    for (int n = 0; n < NR; ++n) { e[n] = __expf(l2[n] - m); s += e[n]; }
    float inv = 1.f / s;
    #pragma unroll
    for (int n = 0; n < NR; ++n) fr[(size_t)p * NR + n] = e[n] * inv;
}

// ---------------- K2: conv + mixture, 3-buffer counted-vmcnt pipeline (T3+T4+T5) ----------------
// GEMM M=1280, N=65536, K=768. Block: 256 thr (4 waves), N=256, M=80; wave tile 80x64.
// 8 K-phases of 32 cins. Buffer (32 KB = 2048 chunks of 16B):
//   X main: chunks 0..1023   = 256 rows x 32 cins (row r = data row l0+r, guard layout)
//   HW:     chunks 1024..2047 = 8 halo chunks (rows l0-2,l0-1 via guard rows) +
//           960 W chunks (240 strips x 4) + 56 dummy chunks (uniform staging pad).
// 3 buffers = 96 KB static LDS (row-3/4's 147 KB never launched; 96 < verified 128 KB).
// Depth-2 prefetch: 8 gload16/wave/stage, in-loop wait = vmcnt(8) (2 stages in flight,
// drain the older). vmcnt never 0 until the last phase (T4). setprio around MFMA (T5).
// Swizzle f(row)=(row>>1)&3 on 64B rows: conflict-free ds_read_b128 (round-2 verified).
#define BUFSH 16384   // shorts per buffer (2048 chunks)
#define HWCH  1024    // chunk offset of halo+W region
__global__ __launch_bounds__(256, 2)
void k_conv(const __hip_bfloat16* __restrict__ xt, const __hip_bfloat16* __restrict__ wb,
            const float* __restrict__ fr, const float* __restrict__ bias,
            float* __restrict__ out) {
    __shared__ __align__(16) short lds[3 * BUFSH];   // 98304 B static
    __shared__ float bs[80];                         // 320 B

    int g = blockIdx.x;
    int pt = ((g >> 7) << 3) | (g & 7);   // XCD swizzle: g=128a+8y+x -> pt=8a+x (bijective)
    int y  = (g >> 3) & 15;
    int p0 = pt * 256;
    int m0 = y * 80, o0 = y * 16;
    int b = p0 >> 12, l0 = p0 & (LL - 1);
    int tid = threadIdx.x;
    int lane = tid & 63, wn = tid >> 6;
    int quad = lane >> 4, l16 = lane & 15;

    const __hip_bfloat16* xb = xt + (size_t)b * (LLP * CIN);

    if (tid < 80) bs[tid] = bias[(tid >> 4) * COUT + o0 + (tid & 15)];

    // ---- per-thread phase-0 global sources (add ph*32 per phase) ----
    int xsrc[4];
    #pragma unroll
    for (int j = 0; j < 4; ++j) {
        int i = j * 256 + tid;                 // X chunk 0..1023
        int row = i >> 2, cs = i & 3;
        int cg = cs ^ ((row >> 1) & 3);
        xsrc[j] = (2 + l0 + row) * CIN + cg * 8;   // guard layout: data row l at index 2+l
    }
    const __hip_bfloat16* hwp[4];
    #pragma unroll
    for (int j = 0; j < 4; ++j) {
        int c = j * 256 + tid;                 // HW chunk 0..1023
        if (c < 8) {                           // halo: xt rows l0,l0+1 = data rows l0-2,l0-1
            int h = c >> 2, cs = c & 3;
            hwp[j] = xb + ((l0 + h) * CIN + cs * 8);
        } else if (c < 968) {                  // W strips 0..239
            int w = c - 8;
            int s = w >> 2, cs = w & 3;
            int cg = cs ^ ((s >> 1) & 3);
            int kh = s / 80, m = s - kh * 80;
            hwp[j] = wb + ((m0 + m) * QK + kh * 256 + cg * 8);
        } else {                               // dummy pad: reload strip s-240 (never read)
            int w = c - 8;
            int s = (w >> 2) - 240, cs = w & 3;
            int cg = cs ^ ((s >> 1) & 3);
            hwp[j] = wb + ((m0 + s) * QK + cg * 8);
        }
    }

    // ---- LDS fragment read offsets (short idx within one buffer) ----
    int boff[3][4], aoff[3][5];
    #pragma unroll
    for (int kh = 0; kh < 3; ++kh) {
        #pragma unroll
        for (int nf = 0; nf < 4; ++nf) {
            int row = wn * 64 + nf * 16 + l16 + kh - 2;   // input slot for this output col
            if (row < 0)
                boff[kh][nf] = (HWCH + (row + 2) * 4 + quad) * 8;   // halo, no swizzle
            else
                boff[kh][nf] = row * 32 + (quad ^ ((row >> 1) & 3)) * 8;
        }
        #pragma unroll
        for (int mf = 0; mf < NR; ++mf) {
            int s = kh * 80 + mf * 16 + l16;
            aoff[kh][mf] = (HWCH + 8 + s * 4 + (quad ^ ((s >> 1) & 3))) * 8;
        }
    }

    floatx4 acc[NR][4];
    #pragma unroll
    for (int mf = 0; mf < NR; ++mf)
        #pragma unroll
        for (int nf = 0; nf < 4; ++nf)
            acc[mf][nf] = (floatx4){0.f, 0.f, 0.f, 0.f};

    auto stage = [&](int buf, int ph) {        // exactly 8 gload16 per wave, all waves
        short* B = &lds[buf * BUFSH];
        const __hip_bfloat16* xp = xb + ph * 32;
        #pragma unroll
        for (int j = 0; j < 4; ++j)
            gload16(xp + xsrc[j], B + (j * 256 + wn * 64) * 8);
        #pragma unroll
        for (int j = 0; j < 4; ++j)
            gload16(hwp[j] + ph * 32, B + (HWCH + j * 256 + wn * 64) * 8);
    };

    auto compute = [&](int buf) {
        const short* B = &lds[buf * BUFSH];
        #pragma unroll
        for (int kh = 0; kh < 3; ++kh) {
            shortx8 bfrag[4], afrag[NR];
            #pragma unroll
            for (int nf = 0; nf < 4; ++nf)
                bfrag[nf] = *(const shortx8*)&B[boff[kh][nf]];
            #pragma unroll
            for (int mf = 0; mf < NR; ++mf)
                afrag[mf] = *(const shortx8*)&B[aoff[kh][mf]];
            #pragma unroll
            for (int mf = 0; mf < NR; ++mf)
                #pragma unroll
                for (int nf = 0; nf < 4; ++nf)
                    acc[mf][nf] = __builtin_amdgcn_mfma_f32_16x16x32_bf16(
                        afrag[mf], bfrag[nf], acc[mf][nf], 0, 0, 0);
        }
    };

    // ---- depth-2 counted-vmcnt pipeline ----
    stage(0, 0);
    stage(1, 1);
    #pragma unroll
    for (int ph = 0; ph < 8; ++ph) {
        if (ph == 0)      asm volatile("s_waitcnt vmcnt(8) lgkmcnt(0)" ::: "memory");
        else if (ph < 7)  asm volatile("s_waitcnt vmcnt(8)" ::: "memory");
        else              asm volatile("s_waitcnt vmcnt(0)" ::: "memory");
        __builtin_amdgcn_s_barrier();          // stage ph landed in every wave -> buf ready
        __builtin_amdgcn_sched_barrier(0);     // pin: nothing hoists above the barrier
        if (ph < 6) stage((ph + 2) % 3, ph + 2);   // overwrites buf read at ph-1 (post-barrier)
        __builtin_amdgcn_s_setprio(1);
        compute(ph % 3);
        __builtin_amdgcn_s_setprio(0);
    }

    // ---- epilogue: out[b, o0+olo, l0+colp] = sum_r fr[p][r]*(acc[r] + bias[r][o]) ----
    #pragma unroll
    for (int nf = 0; nf < 4; ++nf) {
        int colp = wn * 64 + nf * 16 + l16;
        const float* fp = fr + (size_t)(p0 + colp) * NR;
        float f0 = fp[0], f1 = fp[1], f2 = fp[2], f3 = fp[3], f4 = fp[4];
        #pragma unroll
        for (int j = 0; j < 4; ++j) {
            int olo = quad * 4 + j;
            float v = f0 * (acc[0][nf][j] + bs[0 * 16 + olo])
                    + f1 * (acc[1][nf][j] + bs[1 * 16 + olo])
                    + f2 * (acc[2][nf][j] + bs[2 * 16 + olo])
                    + f3 * (acc[3][nf][j] + bs[3 * 16 + olo])
                    + f4 * (acc[4][nf][j] + bs[4 * 16 + olo]);
            out[((size_t)(b * COUT + o0 + olo)) * LL + l0 + colp] = v;
        }
    }
}

extern "C" void kernel_launch(void* const* d_in, const int* in_sizes, int n_in,
                              void* d_out, int out_size, void* d_ws, size_t ws_size,
                              hipStream_t stream) {
    const float* x  = (const float*)d_in[0];
    const float* bk = (const float*)d_in[1];
    const float* bb = (const float*)d_in[2];
    const float* cw = (const float*)d_in[3];
    const float* cb = (const float*)d_in[4];
    float* out = (float*)d_out;

    char* ws = (char*)d_ws;
    __hip_bfloat16* xt = (__hip_bfloat16*)ws;                          // 16*4098*256*2 = 33,570,816 B
    __hip_bfloat16* wb = (__hip_bfloat16*)(ws + 33570816);             //  1,966,080 B
    float*          fr = (float*)(ws + 33570816 + 1966080);            //  1,310,720 B

    k_wprep<<<dim3((NR * COUT * QK + 255) / 256), dim3(256), 0, stream>>>(bk, wb, fr, xt);
    k_tfr<<<dim3(LL / 64, CIN / 64, NB), dim3(256), 0, stream>>>(x, cw, xt, fr);
    k_softmax<<<dim3(NP / 256), dim3(256), 0, stream>>>(cb, fr);
    k_conv<<<dim3(NP / 256 * (COUT / 16)), dim3(256), 0, stream>>>(xt, wb, fr, bb, out);
}